// Round 9
// baseline (197.248 us; speedup 1.0000x reference)
//
#include <hip/hip_runtime.h>
#include <cmath>

#define B_    2
#define T_    512
#define C_    1024
#define E_    8
#define NTOK  1024
#define NPAIR 2048
#define AH_   1024
#define NH_   8
#define HS_   128

typedef unsigned short u16;
typedef __attribute__((ext_vector_type(8))) short bf16x8;
typedef __attribute__((ext_vector_type(4))) float f32x4;

__device__ __forceinline__ u16 f2bf(float f) {
    union { float f; unsigned u; } v; v.f = f;
    unsigned r = v.u + 0x7fff + ((v.u >> 16) & 1);   // RNE
    return (u16)(r >> 16);
}

// async global->LDS, 16B per lane. LDS dest is wave-uniform base + lane*16.
typedef const __attribute__((address_space(1))) unsigned int ga_u32;
typedef __attribute__((address_space(3))) unsigned int ls_u32;
__device__ __forceinline__ void gld_lds16(const u16* g, u16* l) {
    __builtin_amdgcn_global_load_lds((ga_u32*)g, (ls_u32*)l, 16, 0, 0);
}

__device__ __forceinline__ void atomic_fadd(float* p, float v) {
    __hip_atomic_fetch_add(p, v, __ATOMIC_RELAXED, __HIP_MEMORY_SCOPE_AGENT);
}

// ---------------- kernel 1: pack ALL weights + gate + bkv copy, ONE dispatch ------------
// bx < 2304 : pack, TWO 64x64 tiles per block (n0, n0+64) with all 8 float4 loads
//             issued up-front -> 2x in-flight bytes (pack was latency-bound at 2 TB/s).
//             z = bx>>7 (which weight), yy=(bx&127)>>3 -> k0, xx=bx&7 -> n0=xx*128.
// bx in [2304,2560): gate, 4 tokens per block (one per wave); zeroes Out row,
//             writes xb (bf16, vectorized), gates, probs, eass.
// bx == 2560 : bkv copy.
// packed u16 index: (nt*32+ks)*4096 + n_loc*32 + p*8 + j
// content:   W[(ks*32 + g*8 + j)*1024 + nt*128 + n_loc],  g=(p-((n_loc>>1)&3))&3
__global__ __launch_bounds__(256) void pack_gate(
    const float* __restrict__ Win, const float* __restrict__ Wout,
    const float* __restrict__ Wk, const float* __restrict__ Wv,
    u16* __restrict__ wp, u16* __restrict__ woutp, u16* __restrict__ wkvp,
    const float* __restrict__ x, const float* __restrict__ Wg,
    u16* __restrict__ xb, float* __restrict__ gates,
    float* __restrict__ probs, int* __restrict__ eass,
    float* __restrict__ out,
    const float* __restrict__ bk, const float* __restrict__ bv,
    float* __restrict__ bkv)
{
    __shared__ float t[64][65];          // pack: t[k_rel][n_rel]
    int bx = blockIdx.x;
    int tid = threadIdx.x;

    if (bx >= 2304) {
        if (bx == 2560) {
            for (int i = tid; i < 1024; i += 256) {
                bkv[i] = bk[i];
                bkv[i + 1024] = bv[i];
            }
            return;
        }
        // ---- gate path: 4 tokens/block, one per wave; float4 x-loads ----
        int w = tid >> 6, lane = tid & 63;
        int token = (bx - 2304) * 4 + w;
        {
            float4 z4 = {0.f, 0.f, 0.f, 0.f};
            float4* orow = (float4*)(out + (size_t)token * C_);
#pragma unroll
            for (int i = 0; i < 4; i++) orow[lane + i * 64] = z4;
        }
        const float4* xr4 = (const float4*)(x + (size_t)token * C_);
        ushort4* xbr4 = (ushort4*)(xb + (size_t)token * C_);
        float acc[E_];
#pragma unroll
        for (int e = 0; e < E_; e++) acc[e] = 0.f;
#pragma unroll
        for (int it = 0; it < 4; it++) {
            int c4i = lane + it * 64;            // 0..255 float4s
            float4 xv = xr4[c4i];
            ushort4 xo;
            xo.x = f2bf(xv.x); xo.y = f2bf(xv.y);
            xo.z = f2bf(xv.z); xo.w = f2bf(xv.w);
            xbr4[c4i] = xo;
            const float* wr = Wg + (size_t)c4i * 4 * E_;
#pragma unroll
            for (int e = 0; e < E_; e++)
                acc[e] += xv.x * wr[e] + xv.y * wr[e + E_]
                        + xv.z * wr[e + 2 * E_] + xv.w * wr[e + 3 * E_];
        }
#pragma unroll
        for (int e = 0; e < E_; e++) {
            float v = acc[e];
            v += __shfl_xor(v, 32); v += __shfl_xor(v, 16); v += __shfl_xor(v, 8);
            v += __shfl_xor(v, 4);  v += __shfl_xor(v, 2);  v += __shfl_xor(v, 1);
            acc[e] = v;
        }
        if (lane == 0) {
            int i0 = 0; float v0 = acc[0];
            for (int e = 1; e < E_; e++) if (acc[e] > v0) { v0 = acc[e]; i0 = e; }
            int i1 = -1; float v1 = -3.4e38f;
            for (int e = 0; e < E_; e++) if (e != i0 && acc[e] > v1) { v1 = acc[e]; i1 = e; }
            float e1  = __expf(v1 - v0);
            float inv = 1.f / (1.f + e1);
            gates[token * 2 + 0] = inv;
            gates[token * 2 + 1] = e1 * inv;
            float s = 0.f; float pe[E_];
            for (int e = 0; e < E_; e++) { pe[e] = __expf(acc[e] - v0); s += pe[e]; }
            float sinv = 1.f / s;
            for (int e = 0; e < E_; e++) probs[token * E_ + e] = pe[e] * sinv;
            eass[token * 2 + 0] = i0;
            eass[token * 2 + 1] = i1;
        }
        return;
    }

    // ---- pack path: two 64x64 tiles, 8 loads in flight ----
    int z = bx >> 7, r128 = bx & 127, yy = r128 >> 3, xx = r128 & 7;
    const float* src; u16* dst;
    if (z < 8)        { src = Win  + ((size_t)z << 20);       dst = wp    + ((size_t)z << 20); }
    else if (z < 16)  { src = Wout + ((size_t)(z - 8) << 20); dst = woutp + ((size_t)(z - 8) << 20); }
    else if (z == 16) { src = Wk;                             dst = wkvp; }
    else              { src = Wv;                             dst = wkvp + ((size_t)1 << 20); }
    int k0 = yy * 64, n0A = xx * 128;

    float4 va[4], vb[4];
#pragma unroll
    for (int p = 0; p < 4; p++) {
        int e4 = tid + 256 * p;          // 1024 float4 = 64 k-rows x 16 float4
        int r = e4 >> 4, c4 = e4 & 15;
        const float* rowp = &src[(size_t)(k0 + r) * 1024 + n0A + c4 * 4];
        va[p] = *(const float4*)rowp;
        vb[p] = *(const float4*)(rowp + 64);
    }
#pragma unroll
    for (int half = 0; half < 2; half++) {
        if (half) __syncthreads();       // WAR: previous half's readers done
#pragma unroll
        for (int p = 0; p < 4; p++) {
            int e4 = tid + 256 * p;
            int r = e4 >> 4, c4 = e4 & 15;
            float4 v = half ? vb[p] : va[p];
            t[r][c4 * 4 + 0] = v.x; t[r][c4 * 4 + 1] = v.y;
            t[r][c4 * 4 + 2] = v.z; t[r][c4 * 4 + 3] = v.w;
        }
        __syncthreads();
        int c = tid & 63, ks_rel = (tid >> 6) & 1, ph = tid >> 7;
        int n_glob = n0A + half * 64 + c, nt = n_glob >> 7, n_loc = n_glob & 127;
        int ks = (k0 >> 5) + ks_rel;
        u16* ob = dst + (((size_t)(nt * 32 + ks)) << 12) + n_loc * 32;
#pragma unroll
        for (int pp = 0; pp < 2; pp++) {
            int p = ph * 2 + pp;
            int g = (p - ((n_loc >> 1) & 3)) & 3;
            int kb = ks_rel * 32 + g * 8;
            bf16x8 o;
            o[0] = (short)f2bf(t[kb + 0][c]); o[1] = (short)f2bf(t[kb + 1][c]);
            o[2] = (short)f2bf(t[kb + 2][c]); o[3] = (short)f2bf(t[kb + 3][c]);
            o[4] = (short)f2bf(t[kb + 4][c]); o[5] = (short)f2bf(t[kb + 5][c]);
            o[6] = (short)f2bf(t[kb + 6][c]); o[7] = (short)f2bf(t[kb + 7][c]);
            *(bf16x8*)&ob[p * 8] = o;
        }
    }
}

// ---------------- kernel 1b: aux-loss reduce + bucket build (single block) ----------------
__global__ __launch_bounds__(256) void route_kernel(
    const float* __restrict__ probs, const int* __restrict__ eass,
    int* __restrict__ bucket_cnt, int* __restrict__ buckets,
    float* __restrict__ aux_out)
{
    __shared__ float red[256][17];
    __shared__ int lcnt[E_];
    int tid = threadIdx.x;
    float ps[E_], fc[E_];
#pragma unroll
    for (int e = 0; e < E_; e++) { ps[e] = 0.f; fc[e] = 0.f; }
    for (int k = 0; k < 4; k++) {
        int row = tid + k * 256;
#pragma unroll
        for (int e = 0; e < E_; e++) ps[e] += probs[row * E_ + e];
    }
    for (int k = 0; k < 8; k++) {
        int i = tid + k * 256;
        int ea = eass[i];
#pragma unroll
        for (int e = 0; e < E_; e++) fc[e] += (ea == e) ? 1.f : 0.f;
    }
#pragma unroll
    for (int e = 0; e < E_; e++) { red[tid][e] = ps[e]; red[tid][8 + e] = fc[e]; }
    if (tid < E_) lcnt[tid] = 0;
    __syncthreads();
    for (int s = 128; s > 0; s >>= 1) {
        if (tid < s)
#pragma unroll
            for (int j = 0; j < 16; j++) red[tid][j] += red[tid + s][j];
        __syncthreads();
    }
    if (tid == 0) {
        float s = 0.f;
        for (int e = 0; e < E_; e++)
            s += (red[0][e] * (1.f / 1024.f)) * (red[0][8 + e] * (1.f / 1024.f));
        aux_out[0] = (float)E_ * s;
    }
    for (int k = 0; k < 8; k++) {
        int i = tid + k * 256;
        int ea = eass[i];
        int pos = atomicAdd(&lcnt[ea], 1);
        buckets[ea * NPAIR + pos] = i;
    }
    __syncthreads();
    if (tid < E_) bucket_cnt[tid] = lcnt[tid];
}

// ---------------- block-level MFMA mainloop: LDS-staged B, register-direct A ------------
// Proven round-4 structure: double-buffered, one __syncthreads per K-step.
__device__ __forceinline__ void mfma_lds_loop(
    const u16* __restrict__ Aptr,      // per-lane: A + row*1024 + g*8
    const u16* __restrict__ Bsrc,      // block-uniform: packed tile base for this nt
    u16* __restrict__ ldsB,            // [2*8192] u16 = 32KB
    int tid, f32x4 acc[8])
{
    int w = tid >> 6, lane = tid & 63, lm = lane & 15, g = lane >> 4;
    int swz = (g + ((lm >> 1) & 3)) & 3;
    const u16* gstage = Bsrc + w * 512 + lane * 8;   // +kk*8192 +c*2048
    u16* lstage = ldsB + w * 512;                    // wave-uniform dest base
    const u16* bbase = ldsB + lm * 32 + swz * 8;     // frag j: +j*512, sub-ks: +4096

    // prologue: stage kk=0 into buf0
#pragma unroll
    for (int c = 0; c < 4; c++)
        gld_lds16(gstage + c * 2048, lstage + c * 2048);

    bf16x8 a0 = *(const bf16x8*)(Aptr);
    bf16x8 a1 = *(const bf16x8*)(Aptr + 32);
    __syncthreads();   // compiler drains vmcnt(0) before barrier -> buf0 ready

#pragma unroll
    for (int kk = 0; kk < 16; kk++) {
        int cur = kk & 1;
        if (kk < 15) {
            const u16* gs = gstage + (size_t)(kk + 1) * 8192;
            u16* ls = lstage + ((kk + 1) & 1) * 8192;
#pragma unroll
            for (int c = 0; c < 4; c++)
                gld_lds16(gs + c * 2048, ls + c * 2048);
        }
        bf16x8 na0, na1;
        if (kk < 15) {
            na0 = *(const bf16x8*)(Aptr + (size_t)(2 * kk + 2) * 32);
            na1 = *(const bf16x8*)(Aptr + (size_t)(2 * kk + 3) * 32);
        }
        const u16* bb = bbase + cur * 8192;
#pragma unroll
        for (int j = 0; j < 8; j++) {
            bf16x8 b0 = *(const bf16x8*)(bb + j * 512);
            acc[j] = __builtin_amdgcn_mfma_f32_16x16x32_bf16(a0, b0, acc[j], 0, 0, 0);
        }
#pragma unroll
        for (int j = 0; j < 8; j++) {
            bf16x8 b1 = *(const bf16x8*)(bb + 4096 + j * 512);
            acc[j] = __builtin_amdgcn_mfma_f32_16x16x32_bf16(a1, b1, acc[j], 0, 0, 0);
        }
        a0 = na0; a1 = na1;
        __syncthreads();   // stage for next buf drained; all waves done reading cur
    }
}

// ---------------- fused KV (dense) + q (routed) GEMM, LDS-B-staged ----------------------
// Identity block mapping. bx<256: KV (mt=bx&15, nt=bx>>4). nt<8 -> K -> Kb.
// nt>=8 -> V -> transpose in ldsB -> Vtb (vtrans fused). bx>=256: q routed -> Qb.
__global__ __launch_bounds__(256) void gemm_fused(
    const u16* __restrict__ xb, const u16* __restrict__ Wkv_p,
    const float* __restrict__ bkv, const u16* __restrict__ Win_p,
    const int* __restrict__ bucket_cnt, const int* __restrict__ buckets,
    u16* __restrict__ Kb, u16* __restrict__ Vtb, u16* __restrict__ Qb)
{
    __shared__ __align__(16) u16 ldsB[2 * 8192];
    int bx = blockIdx.x;
    int tid = threadIdx.x;
    int w = tid >> 6, lane = tid & 63, lm = lane & 15, g = lane >> 4;
    bool isKV = bx < 256;
    int e = 0, mt, nt, cnt;
    const u16* Wp;
    if (isKV) {
        mt = bx & 15; nt = bx >> 4; cnt = NTOK; Wp = Wkv_p;
    } else {
        int b2 = bx - 256;
        mt = b2 >> 6; e = (b2 & 63) >> 3; nt = b2 & 7;
        cnt = bucket_cnt[e];
        Wp = Win_p + ((size_t)e << 20);
    }
    int m0 = mt * 64;
    if (m0 >= cnt) return;
    int strip = m0 + w * 16;

    // A row (for loading) and D rows (for storing)
    int arow, drow[4];
    if (isKV) {
        arow = strip + lm;
#pragma unroll
        for (int r = 0; r < 4; r++) drow[r] = strip + g * 4 + r;
    } else {
        int ai = strip + lm;
        arow = buckets[e * NPAIR + (ai < cnt ? ai : cnt - 1)] >> 1;   // token
#pragma unroll
        for (int r = 0; r < 4; r++) {
            int di = strip + g * 4 + r;
            drow[r] = (di < cnt) ? buckets[e * NPAIR + di] : -1;      // pair
        }
    }
    const u16* Aptr = xb + (size_t)arow * 1024 + g * 8;
    const u16* Bsrc = Wp + (((size_t)(nt * 32)) << 12);

    f32x4 acc[8];
#pragma unroll
    for (int j = 0; j < 8; j++) acc[j] = 0;

    mfma_lds_loop(Aptr, Bsrc, ldsB, tid, acc);

    if (isKV && nt >= 8) {
        // ---- fused V transpose: stage bf16(v+bias) tile [64 tok][128 d] in ldsB ----
        // (mainloop ends with __syncthreads -> ldsB free for reuse)
        u16* tt = ldsB;                    // 64*136*2 = 17408 B <= 32768
#pragma unroll
        for (int reg = 0; reg < 4; reg++) {
            int r_loc = w * 16 + g * 4 + reg;
#pragma unroll
            for (int j = 0; j < 8; j++) {
                int col = nt * 128 + j * 16 + lm;
                tt[r_loc * 136 + j * 16 + lm] = f2bf(acc[j][reg] + bkv[col]);
            }
        }
        __syncthreads();
        int hh = nt - 8;
        int tb = m0 >> 9, tj0 = m0 & 511;
        int bh = tb * 8 + hh;
#pragma unroll
        for (int p = 0; p < 4; p++) {
            int cc = tid + 256 * p;            // 0..1023
            int dr = cc >> 3, j8 = cc & 7;
            bf16x8 o;
#pragma unroll
            for (int k = 0; k < 8; k++) o[k] = (short)tt[(j8 * 8 + k) * 136 + dr];
            *(bf16x8*)&Vtb[((size_t)bh * 128 + dr) * 512 + tj0 + j8 * 8] = o;
        }
        return;
    }

    // epilogue: D row (within frag) = g*4+reg, col = nt*128 + j*16 + lm
#pragma unroll
    for (int reg = 0; reg < 4; reg++) {
        int di = strip + g * 4 + reg;
        if (isKV || di < cnt) {
            int orow = drow[reg];
            if (!isKV && orow < 0) continue;
#pragma unroll
            for (int j = 0; j < 8; j++) {
                int col = nt * 128 + j * 16 + lm;
                float v = acc[j][reg];
                if (isKV) {
                    v += bkv[col];                     // nt<8 -> K half
                    int tb = orow >> 9, tj = orow & 511;
                    int hh = col >> 7, dd = col & 127;
                    Kb[(((size_t)(tb * 8 + hh) * 512 + tj) << 7) + dd] = f2bf(v);
                } else {
                    int pb = orow >> 10, pi = (orow >> 1) & 511, ps = orow & 1;
                    int hh = col >> 7, dd = col & 127;
                    Qb[((((size_t)(pb * 16 + ps * 8 + hh)) * 512 + pi) << 7) + dd] = f2bf(v);
                }
            }
        }
    }
}

// ---------------- W_out routed GEMM, LDS-B-staged, atomic fp32 add into Out -------------
__global__ __launch_bounds__(256) void gemm_wout(
    const u16* __restrict__ yb, const u16* __restrict__ Wout_p,
    const int* __restrict__ bucket_cnt, const int* __restrict__ buckets,
    float* __restrict__ Out)
{
    __shared__ __align__(16) u16 ldsB[2 * 8192];
    int bx = blockIdx.x;
    int tid = threadIdx.x;
    int w = tid >> 6, lane = tid & 63, lm = lane & 15, g = lane >> 4;
    int mt = bx >> 6, e = (bx & 63) >> 3, nt = bx & 7;
    int cnt = bucket_cnt[e];
    int m0 = mt * 64;
    if (m0 >= cnt) return;
    int strip = m0 + w * 16;

    int ai = strip + lm;
    int arow = buckets[e * NPAIR + (ai < cnt ? ai : cnt - 1)];
    int drow[4];
#pragma unroll
    for (int r = 0; r < 4; r++) {
        int di = strip + g * 4 + r;
        drow[r] = (di < cnt) ? buckets[e * NPAIR + di] : -1;
    }
    const u16* Aptr = yb + (size_t)arow * 1024 + g * 8;
    const u16* Bsrc = Wout_p + ((size_t)e << 20) + (((size_t)(nt * 32)) << 12);

    f32x4 acc[8];
#pragma unroll
    for (int j = 0; j < 8; j++) acc[j] = 0;

    mfma_lds_loop(Aptr, Bsrc, ldsB, tid, acc);

    // each valid pair-row appears exactly once across the grid -> exactly-once adds
#pragma unroll
    for (int reg = 0; reg < 4; reg++) {
        int orow = drow[reg];
        if (orow >= 0) {
            float* od = Out + (size_t)(orow >> 1) * 1024;
#pragma unroll
            for (int j = 0; j < 8; j++) {
                int col = nt * 128 + j * 16 + lm;
                atomic_fadd(&od[col], acc[j][reg]);
            }
        }
    }
}

// ---------------- stick-breaking flash attention, MFMA, base-2 softmax ----------------
// grid (32, 16): one i-tile per block; heavy/light pairing per CU.
// 2 barriers/iter: K/V double-buffered in LDS; T14 async-stage split; T5 setprio.
__global__ __launch_bounds__(256) void attn_kernel(
    const u16* __restrict__ Qb, const u16* __restrict__ Kb,
    const u16* __restrict__ Vtb, const float* __restrict__ gates,
    u16* __restrict__ yb)
{
    __shared__ __align__(16) u16 Qs[32 * 136];
    __shared__ __align__(16) u16 Ks[2][32 * 136];
    __shared__ __align__(16) u16 Vts[2][128 * 40];
    __shared__ __align__(16) float sw[32 * 36];
    __shared__ __align__(16) u16 wt[32 * 40];

    int combo = blockIdx.x;
    int b = combo >> 4, slot = (combo >> 3) & 1, h = combo & 7;
    int bh = b * 8 + h;
    const u16* Qbase = Qb  + ((size_t)combo << 16);
    const u16* Kbase = Kb  + ((size_t)bh << 16);
    const u16* Vbase = Vtb + ((size_t)bh << 16);

    int tid = threadIdx.x;
    int w = tid >> 6, lane = tid & 63, lm = lane & 15, g = lane >> 4;
    int mh = w >> 1, nh = w & 1, dsel = w & 1;
    int srow = tid >> 3, st = tid & 7;
    int rowlane = lane & 56;
    const float SCALE2 = 0.127517433f;   // (1/sqrt(128)) * log2(e)

    int by = blockIdx.y;
    int it = (by < 8) ? (15 - by) : (by - 8);   // heavy first; (15-y, y) pair per CU
    int i0 = it * 32;

    // K/V staging geometry (split into g2r + r2lds)
    int kr0 = tid >> 4, kc = (tid & 15) * 8;    // K: rows kr0, kr0+16
    int vr0 = tid >> 2, vc = (tid & 3) * 8;     // V: d-rows vr0, vr0+64
    bf16x8 kreg[2], vreg[2];

#define LDKV(j0_)                                                                  \
    {                                                                              \
        _Pragma("unroll")                                                          \
        for (int p = 0; p < 2; p++) {                                              \
            kreg[p] = *(const bf16x8*)&Kbase[(size_t)((j0_) + kr0 + 16 * p) * 128 + kc]; \
            vreg[p] = *(const bf16x8*)&Vbase[(size_t)(vr0 + 64 * p) * 512 + (j0_) + vc]; \
        }                                                                          \
    }
#define STKV(buf_)                                                                 \
    {                                                                              \
        _Pragma("unroll")                                                          \
        for (int p = 0; p < 2; p++) {                                              \
            *(bf16x8*)&Ks[buf_][(kr0 + 16 * p) * 136 + kc] = kreg[p];              \
            *(bf16x8*)&Vts[buf_][(vr0 + 64 * p) * 40 + vc] = vreg[p];              \
        }                                                                          \
    }

    // prologue: Q + first K/V tile into buf 0
#pragma unroll
    for (int p = 0; p < 2; p++) {
        int c = tid + 256 * p;
        int r = c >> 4, c8 = c & 15;
        *(bf16x8*)&Qs[r * 136 + c8 * 8] =
            *(const bf16x8*)&Qbase[(size_t)(i0 + r) * 128 + c8 * 8];
    }
    LDKV(i0);
    STKV(0);
    __syncthreads();

    f32x4 pacc[4];
#pragma unroll
    for (int q = 0; q < 4; q++) pacc[q] = 0;
    float running = 0.f;
    int pbuf = 0;

    for (int jt = it; jt >= 0; jt--) {
        int j0 = jt * 32;
        f32x4 sacc = 0;
        __builtin_amdgcn_s_setprio(1);
#pragma unroll
        for (int ks = 0; ks < 4; ks++) {
            bf16x8 aq = *(const bf16x8*)&Qs[(mh * 16 + lm) * 136 + ks * 32 + g * 8];
            bf16x8 bk = *(const bf16x8*)&Ks[pbuf][(nh * 16 + lm) * 136 + ks * 32 + g * 8];
            sacc = __builtin_amdgcn_mfma_f32_16x16x32_bf16(aq, bk, sacc, 0, 0, 0);
        }
        __builtin_amdgcn_s_setprio(0);
#pragma unroll
        for (int reg = 0; reg < 4; reg++)
            sw[(mh * 16 + g * 4 + reg) * 36 + nh * 16 + lm] = sacc[reg] * SCALE2;
        if (jt > 0) LDKV(j0 - 32);          // issue global loads; latency hides below
        __syncthreads();                     // sw ready
        {
            float4 sv = *(const float4*)&sw[srow * 36 + st * 4];
            float sarr[4] = {sv.x, sv.y, sv.z, sv.w};
            int ig = i0 + srow;
            float lsig[4], lb[4];
#pragma unroll
            for (int c2 = 0; c2 < 4; c2++) {
                int jg = j0 + st * 4 + c2;
                float sc = sarr[c2];                 // base-2 log space
                float a  = fabsf(sc);
                float tl = __builtin_amdgcn_logf(1.f + __builtin_amdgcn_exp2f(-a));
                lsig[c2] = (sc >= 0.f) ? -tl : sc - tl;       // log2 sigmoid
                lb[c2]   = (jg <= ig) ? -(tl + fmaxf(sc, 0.f)) : 0.f;  // log2 beta
            }
            float suf[4];
            suf[3] = 0.f;
            suf[2] = lb[3];
            suf[1] = lb[2] + lb[3];
            suf[0] = lb[1] + suf[1];
            float total = lb[0] + suf[0];
            float incl = total;
            float y1 = __shfl_down(incl, 1, 64); if (st < 7) incl += y1;
            float y2 = __shfl_down(incl, 2, 64); if (st < 6) incl += y2;
            float y4 = __shfl_down(incl, 4, 64); if (st < 4) incl += y4;
            float basev = (incl - total) + running;
            ushort4 wo;
            float wv;
            int jgc = j0 + st * 4;
            wv = (jgc + 0 <= ig) ? __builtin_amdgcn_exp2f(lsig[0] + suf[0] + basev) : 0.f; wo.x = f2bf(wv);
            wv = (jgc + 1 <= ig) ? __builtin_amdgcn_exp2f(lsig[1] + suf[1] + basev) : 0.f; wo.y = f2bf(wv);
            wv = (jgc + 2 <= ig) ? __builtin_amdgcn_exp2f(lsig[2] + suf[2] + basev) : 0.f; wo.z = f2bf(wv);
            wv = (jgc + 3 <= ig) ? __builtin_amdgcn_exp2f(lsig[3] + suf[3] + basev) : 0.f; wo.w = f2bf(wv);
            running += __shfl(incl, rowlane, 64);
            *(ushort4*)&wt[srow * 40 + st * 4] = wo;
        }
        if (jt > 0) STKV(pbuf ^ 1);          // reg->LDS into other buffer
        __syncthreads();                     // wt ready + next K/V buffer ready
        bf16x8 aw = *(const bf16x8*)&wt[(mh * 16 + lm) * 40 + g * 8];
        __builtin_amdgcn_s_setprio(1);
#pragma unroll
        for (int q = 0; q < 4; q++) {
            int dt = q * 2 + dsel;
            bf16x8 bv8 = *(const bf16x8*)&Vts[pbuf][(dt * 16 + lm) * 40 + g * 8];
            pacc[q] = __builtin_amdgcn_mfma_f32_16x16x32_bf16(aw, bv8, pacc[q], 0, 0, 0);
        }
        __builtin_amdgcn_s_setprio(0);
        pbuf ^= 1;
    }
#pragma unroll
    for (int reg = 0; reg < 4; reg++) {
        int i = i0 + mh * 16 + g * 4 + reg;
        size_t pair = ((size_t)(b * 512 + i)) * 2 + slot;
        float gt = gates[pair];
#pragma unroll
        for (int q = 0; q < 4; q++) {
            int d = (q * 2 + dsel) * 16 + lm;
            yb[pair * 1024 + h * 128 + d] = f2bf(pacc[q][reg] * gt);
        }
    }
#undef LDKV
#undef STKV
}

extern "C" void kernel_launch(void* const* d_in, const int* in_sizes, int n_in,
                              void* d_out, int out_size, void* d_ws, size_t ws_size,
                              hipStream_t stream)
{
    const float* x     = (const float*)d_in[0];
    const float* Wg    = (const float*)d_in[1];
    const float* W_in  = (const float*)d_in[2];
    const float* W_out = (const float*)d_in[3];
    const float* Wk    = (const float*)d_in[4];
    const float* bk    = (const float*)d_in[5];
    const float* Wv    = (const float*)d_in[6];
    const float* bv    = (const float*)d_in[7];

    char* ws = (char*)d_ws;
    int*   bucket_cnt = (int*)ws;
    size_t off = 256;
    float* gates = (float*)(ws + off); off += (size_t)NPAIR * 4;
    int* buckets = (int*)(ws + off);   off += (size_t)E_ * NPAIR * 4;
    float* bkv   = (float*)(ws + off); off += 2048 * 4;
    float* probs = (float*)(ws + off); off += (size_t)NTOK * E_ * 4;
    int*   eass  = (int*)(ws + off);   off += (size_t)NPAIR * 4;
    off = (off + 255) & ~(size_t)255;
    u16* xb     = (u16*)(ws + off); off += (size_t)NTOK * C_ * 2;
    u16* Wkv_p  = (u16*)(ws + off); off += (size_t)2048 * 1024 * 2;
    u16* wp     = (u16*)(ws + off); off += (size_t)E_ * 1024 * 1024 * 2;   // W_in packed
    u16* wout_p = (u16*)(ws + off); off += (size_t)E_ * 1024 * 1024 * 2;   // W_out packed
    u16* yb     = (u16*)(ws + off); off += (size_t)NPAIR * AH_ * 2;
    u16* Qbuf   = (u16*)(ws + off); off += (size_t)32 * 512 * 128 * 2;
    u16* Kbuf   = (u16*)(ws + off); off += (size_t)16 * 512 * 128 * 2;
    u16* Vtbuf  = (u16*)(ws + off); off += (size_t)16 * 128 * 512 * 2;

    pack_gate<<<2561, 256, 0, stream>>>(W_in, W_out, Wk, Wv, wp, wout_p, Wkv_p,
                                        x, Wg, xb, gates, probs, eass,
                                        (float*)d_out, bk, bv, bkv);
    route_kernel<<<1, 256, 0, stream>>>(probs, eass, bucket_cnt, buckets,
                                        (float*)d_out + (out_size - 1));

    // fused KV (256 blocks, V transposed in epilogue) + q (2048 logical blocks)
    gemm_fused<<<256 + 2048, 256, 0, stream>>>(xb, Wkv_p, bkv, wp, bucket_cnt,
                                               buckets, Kbuf, Vtbuf, Qbuf);

    attn_kernel<<<dim3(32, 16), 256, 0, stream>>>(Qbuf, Kbuf, Vtbuf, gates, yb);

    gemm_wout<<<2048, 256, 0, stream>>>(yb, wout_p, bucket_cnt, buckets,
                                        (float*)d_out);
}

// Round 10
// 190.340 us; speedup vs baseline: 1.0363x; 1.0363x over previous
//
#include <hip/hip_runtime.h>
#include <cmath>

#define B_    2
#define T_    512
#define C_    1024
#define E_    8
#define NTOK  1024
#define NPAIR 2048
#define AH_   1024
#define NH_   8
#define HS_   128

typedef unsigned short u16;
typedef __attribute__((ext_vector_type(8))) short bf16x8;
typedef __attribute__((ext_vector_type(4))) float f32x4;

__device__ __forceinline__ u16 f2bf(float f) {
    union { float f; unsigned u; } v; v.f = f;
    unsigned r = v.u + 0x7fff + ((v.u >> 16) & 1);   // RNE
    return (u16)(r >> 16);
}

// async global->LDS, 16B per lane. LDS dest is wave-uniform base + lane*16.
typedef const __attribute__((address_space(1))) unsigned int ga_u32;
typedef __attribute__((address_space(3))) unsigned int ls_u32;
__device__ __forceinline__ void gld_lds16(const u16* g, u16* l) {
    __builtin_amdgcn_global_load_lds((ga_u32*)g, (ls_u32*)l, 16, 0, 0);
}

__device__ __forceinline__ void atomic_fadd(float* p, float v) {
    __hip_atomic_fetch_add(p, v, __ATOMIC_RELAXED, __HIP_MEMORY_SCOPE_AGENT);
}

// ---------------- kernel 1: pack ALL weights + gate + bkv copy, ONE dispatch ------------
// bx < 2304 : pack, TWO 64x64 tiles per block (n0, n0+64), 8 float4 loads in flight.
//             Output stage COALESCED: thread q -> (c=q>>2, p=q&3), both ks_rel; each
//             wave writes 1KB contiguous per burst (was 16-32B at 64B stride -> 2x L2
//             write transactions). Pure bijective remap, content formula unchanged.
// bx in [2304,2560): gate, 4 tokens per block (one per wave); zeroes Out row,
//             writes xb (bf16, vectorized), gates, probs, eass.
// bx == 2560 : bkv copy.
// packed u16 index: (nt*32+ks)*4096 + n_loc*32 + p*8 + j
// content:   W[(ks*32 + g*8 + j)*1024 + nt*128 + n_loc],  g=(p-((n_loc>>1)&3))&3
__global__ __launch_bounds__(256) void pack_gate(
    const float* __restrict__ Win, const float* __restrict__ Wout,
    const float* __restrict__ Wk, const float* __restrict__ Wv,
    u16* __restrict__ wp, u16* __restrict__ woutp, u16* __restrict__ wkvp,
    const float* __restrict__ x, const float* __restrict__ Wg,
    u16* __restrict__ xb, float* __restrict__ gates,
    float* __restrict__ probs, int* __restrict__ eass,
    float* __restrict__ out,
    const float* __restrict__ bk, const float* __restrict__ bv,
    float* __restrict__ bkv)
{
    __shared__ float t[64][65];          // pack: t[k_rel][n_rel]
    int bx = blockIdx.x;
    int tid = threadIdx.x;

    if (bx >= 2304) {
        if (bx == 2560) {
            for (int i = tid; i < 1024; i += 256) {
                bkv[i] = bk[i];
                bkv[i + 1024] = bv[i];
            }
            return;
        }
        // ---- gate path: 4 tokens/block, one per wave; float4 x-loads ----
        int w = tid >> 6, lane = tid & 63;
        int token = (bx - 2304) * 4 + w;
        {
            float4 z4 = {0.f, 0.f, 0.f, 0.f};
            float4* orow = (float4*)(out + (size_t)token * C_);
#pragma unroll
            for (int i = 0; i < 4; i++) orow[lane + i * 64] = z4;
        }
        const float4* xr4 = (const float4*)(x + (size_t)token * C_);
        ushort4* xbr4 = (ushort4*)(xb + (size_t)token * C_);
        float acc[E_];
#pragma unroll
        for (int e = 0; e < E_; e++) acc[e] = 0.f;
#pragma unroll
        for (int it = 0; it < 4; it++) {
            int c4i = lane + it * 64;            // 0..255 float4s
            float4 xv = xr4[c4i];
            ushort4 xo;
            xo.x = f2bf(xv.x); xo.y = f2bf(xv.y);
            xo.z = f2bf(xv.z); xo.w = f2bf(xv.w);
            xbr4[c4i] = xo;
            const float* wr = Wg + (size_t)c4i * 4 * E_;
#pragma unroll
            for (int e = 0; e < E_; e++)
                acc[e] += xv.x * wr[e] + xv.y * wr[e + E_]
                        + xv.z * wr[e + 2 * E_] + xv.w * wr[e + 3 * E_];
        }
#pragma unroll
        for (int e = 0; e < E_; e++) {
            float v = acc[e];
            v += __shfl_xor(v, 32); v += __shfl_xor(v, 16); v += __shfl_xor(v, 8);
            v += __shfl_xor(v, 4);  v += __shfl_xor(v, 2);  v += __shfl_xor(v, 1);
            acc[e] = v;
        }
        if (lane == 0) {
            int i0 = 0; float v0 = acc[0];
            for (int e = 1; e < E_; e++) if (acc[e] > v0) { v0 = acc[e]; i0 = e; }
            int i1 = -1; float v1 = -3.4e38f;
            for (int e = 0; e < E_; e++) if (e != i0 && acc[e] > v1) { v1 = acc[e]; i1 = e; }
            float e1  = __expf(v1 - v0);
            float inv = 1.f / (1.f + e1);
            gates[token * 2 + 0] = inv;
            gates[token * 2 + 1] = e1 * inv;
            float s = 0.f; float pe[E_];
            for (int e = 0; e < E_; e++) { pe[e] = __expf(acc[e] - v0); s += pe[e]; }
            float sinv = 1.f / s;
            for (int e = 0; e < E_; e++) probs[token * E_ + e] = pe[e] * sinv;
            eass[token * 2 + 0] = i0;
            eass[token * 2 + 1] = i1;
        }
        return;
    }

    // ---- pack path: two 64x64 tiles, 8 loads in flight, coalesced packed stores ----
    int z = bx >> 7, r128 = bx & 127, yy = r128 >> 3, xx = r128 & 7;
    const float* src; u16* dst;
    if (z < 8)        { src = Win  + ((size_t)z << 20);       dst = wp    + ((size_t)z << 20); }
    else if (z < 16)  { src = Wout + ((size_t)(z - 8) << 20); dst = woutp + ((size_t)(z - 8) << 20); }
    else if (z == 16) { src = Wk;                             dst = wkvp; }
    else              { src = Wv;                             dst = wkvp + ((size_t)1 << 20); }
    int k0 = yy * 64, n0A = xx * 128;

    float4 va[4], vb[4];
#pragma unroll
    for (int p = 0; p < 4; p++) {
        int e4 = tid + 256 * p;          // 1024 float4 = 64 k-rows x 16 float4
        int r = e4 >> 4, c4 = e4 & 15;
        const float* rowp = &src[(size_t)(k0 + r) * 1024 + n0A + c4 * 4];
        va[p] = *(const float4*)rowp;
        vb[p] = *(const float4*)(rowp + 64);
    }
#pragma unroll
    for (int half = 0; half < 2; half++) {
        if (half) __syncthreads();       // WAR: previous half's readers done
#pragma unroll
        for (int p = 0; p < 4; p++) {
            int e4 = tid + 256 * p;
            int r = e4 >> 4, c4 = e4 & 15;
            float4 v = half ? vb[p] : va[p];
            t[r][c4 * 4 + 0] = v.x; t[r][c4 * 4 + 1] = v.y;
            t[r][c4 * 4 + 2] = v.z; t[r][c4 * 4 + 3] = v.w;
        }
        __syncthreads();
        // thread q -> chunk (c = q>>2, p = q&3); both ks_rel. Wave writes bytes
        // half*4096 + q*16 within each (nt,ks) 8KB region -> fully coalesced.
        int q = tid;
        int c = q >> 2, p = q & 3;
        int n_glob = n0A + half * 64 + c;
        int nt = n_glob >> 7, n_loc = n_glob & 127;
        int g = (p - ((n_loc >> 1) & 3)) & 3;
#pragma unroll
        for (int ks_rel = 0; ks_rel < 2; ks_rel++) {
            int ks = (k0 >> 5) + ks_rel;
            int kb = ks_rel * 32 + g * 8;
            u16* ob = dst + (((size_t)(nt * 32 + ks)) << 12) + n_loc * 32 + p * 8;
            bf16x8 o;
            o[0] = (short)f2bf(t[kb + 0][c]); o[1] = (short)f2bf(t[kb + 1][c]);
            o[2] = (short)f2bf(t[kb + 2][c]); o[3] = (short)f2bf(t[kb + 3][c]);
            o[4] = (short)f2bf(t[kb + 4][c]); o[5] = (short)f2bf(t[kb + 5][c]);
            o[6] = (short)f2bf(t[kb + 6][c]); o[7] = (short)f2bf(t[kb + 7][c]);
            *(bf16x8*)ob = o;
        }
    }
}

// ---------------- kernel 1b: aux-loss reduce + bucket build (single block) ----------------
__global__ __launch_bounds__(256) void route_kernel(
    const float* __restrict__ probs, const int* __restrict__ eass,
    int* __restrict__ bucket_cnt, int* __restrict__ buckets,
    float* __restrict__ aux_out)
{
    __shared__ float red[256][17];
    __shared__ int lcnt[E_];
    int tid = threadIdx.x;
    float ps[E_], fc[E_];
#pragma unroll
    for (int e = 0; e < E_; e++) { ps[e] = 0.f; fc[e] = 0.f; }
    for (int k = 0; k < 4; k++) {
        int row = tid + k * 256;
#pragma unroll
        for (int e = 0; e < E_; e++) ps[e] += probs[row * E_ + e];
    }
    for (int k = 0; k < 8; k++) {
        int i = tid + k * 256;
        int ea = eass[i];
#pragma unroll
        for (int e = 0; e < E_; e++) fc[e] += (ea == e) ? 1.f : 0.f;
    }
#pragma unroll
    for (int e = 0; e < E_; e++) { red[tid][e] = ps[e]; red[tid][8 + e] = fc[e]; }
    if (tid < E_) lcnt[tid] = 0;
    __syncthreads();
    for (int s = 128; s > 0; s >>= 1) {
        if (tid < s)
#pragma unroll
            for (int j = 0; j < 16; j++) red[tid][j] += red[tid + s][j];
        __syncthreads();
    }
    if (tid == 0) {
        float s = 0.f;
        for (int e = 0; e < E_; e++)
            s += (red[0][e] * (1.f / 1024.f)) * (red[0][8 + e] * (1.f / 1024.f));
        aux_out[0] = (float)E_ * s;
    }
    for (int k = 0; k < 8; k++) {
        int i = tid + k * 256;
        int ea = eass[i];
        int pos = atomicAdd(&lcnt[ea], 1);
        buckets[ea * NPAIR + pos] = i;
    }
    __syncthreads();
    if (tid < E_) bucket_cnt[tid] = lcnt[tid];
}

// ---------------- block-level MFMA mainloop: LDS-staged B, register-direct A ------------
// Proven round-4 structure: double-buffered, one __syncthreads per K-step.
__device__ __forceinline__ void mfma_lds_loop(
    const u16* __restrict__ Aptr,      // per-lane: A + row*1024 + g*8
    const u16* __restrict__ Bsrc,      // block-uniform: packed tile base for this nt
    u16* __restrict__ ldsB,            // [2*8192] u16 = 32KB
    int tid, f32x4 acc[8])
{
    int w = tid >> 6, lane = tid & 63, lm = lane & 15, g = lane >> 4;
    int swz = (g + ((lm >> 1) & 3)) & 3;
    const u16* gstage = Bsrc + w * 512 + lane * 8;   // +kk*8192 +c*2048
    u16* lstage = ldsB + w * 512;                    // wave-uniform dest base
    const u16* bbase = ldsB + lm * 32 + swz * 8;     // frag j: +j*512, sub-ks: +4096

    // prologue: stage kk=0 into buf0
#pragma unroll
    for (int c = 0; c < 4; c++)
        gld_lds16(gstage + c * 2048, lstage + c * 2048);

    bf16x8 a0 = *(const bf16x8*)(Aptr);
    bf16x8 a1 = *(const bf16x8*)(Aptr + 32);
    __syncthreads();   // compiler drains vmcnt(0) before barrier -> buf0 ready

#pragma unroll
    for (int kk = 0; kk < 16; kk++) {
        int cur = kk & 1;
        if (kk < 15) {
            const u16* gs = gstage + (size_t)(kk + 1) * 8192;
            u16* ls = lstage + ((kk + 1) & 1) * 8192;
#pragma unroll
            for (int c = 0; c < 4; c++)
                gld_lds16(gs + c * 2048, ls + c * 2048);
        }
        bf16x8 na0, na1;
        if (kk < 15) {
            na0 = *(const bf16x8*)(Aptr + (size_t)(2 * kk + 2) * 32);
            na1 = *(const bf16x8*)(Aptr + (size_t)(2 * kk + 3) * 32);
        }
        const u16* bb = bbase + cur * 8192;
#pragma unroll
        for (int j = 0; j < 8; j++) {
            bf16x8 b0 = *(const bf16x8*)(bb + j * 512);
            acc[j] = __builtin_amdgcn_mfma_f32_16x16x32_bf16(a0, b0, acc[j], 0, 0, 0);
        }
#pragma unroll
        for (int j = 0; j < 8; j++) {
            bf16x8 b1 = *(const bf16x8*)(bb + 4096 + j * 512);
            acc[j] = __builtin_amdgcn_mfma_f32_16x16x32_bf16(a1, b1, acc[j], 0, 0, 0);
        }
        a0 = na0; a1 = na1;
        __syncthreads();   // stage for next buf drained; all waves done reading cur
    }
}

// ---------------- fused KV (dense) + q (routed) GEMM, LDS-B-staged ----------------------
// Identity block mapping. bx<256: KV (mt=bx&15, nt=bx>>4). nt<8 -> K -> Kb.
// nt>=8 -> V -> transpose in ldsB -> Vtb (vtrans fused). bx>=256: q routed -> Qb.
__global__ __launch_bounds__(256) void gemm_fused(
    const u16* __restrict__ xb, const u16* __restrict__ Wkv_p,
    const float* __restrict__ bkv, const u16* __restrict__ Win_p,
    const int* __restrict__ bucket_cnt, const int* __restrict__ buckets,
    u16* __restrict__ Kb, u16* __restrict__ Vtb, u16* __restrict__ Qb)
{
    __shared__ __align__(16) u16 ldsB[2 * 8192];
    int bx = blockIdx.x;
    int tid = threadIdx.x;
    int w = tid >> 6, lane = tid & 63, lm = lane & 15, g = lane >> 4;
    bool isKV = bx < 256;
    int e = 0, mt, nt, cnt;
    const u16* Wp;
    if (isKV) {
        mt = bx & 15; nt = bx >> 4; cnt = NTOK; Wp = Wkv_p;
    } else {
        int b2 = bx - 256;
        mt = b2 >> 6; e = (b2 & 63) >> 3; nt = b2 & 7;
        cnt = bucket_cnt[e];
        Wp = Win_p + ((size_t)e << 20);
    }
    int m0 = mt * 64;
    if (m0 >= cnt) return;
    int strip = m0 + w * 16;

    // A row (for loading) and D rows (for storing)
    int arow, drow[4];
    if (isKV) {
        arow = strip + lm;
#pragma unroll
        for (int r = 0; r < 4; r++) drow[r] = strip + g * 4 + r;
    } else {
        int ai = strip + lm;
        arow = buckets[e * NPAIR + (ai < cnt ? ai : cnt - 1)] >> 1;   // token
#pragma unroll
        for (int r = 0; r < 4; r++) {
            int di = strip + g * 4 + r;
            drow[r] = (di < cnt) ? buckets[e * NPAIR + di] : -1;      // pair
        }
    }
    const u16* Aptr = xb + (size_t)arow * 1024 + g * 8;
    const u16* Bsrc = Wp + (((size_t)(nt * 32)) << 12);

    f32x4 acc[8];
#pragma unroll
    for (int j = 0; j < 8; j++) acc[j] = 0;

    mfma_lds_loop(Aptr, Bsrc, ldsB, tid, acc);

    if (isKV && nt >= 8) {
        // ---- fused V transpose: stage bf16(v+bias) tile [64 tok][128 d] in ldsB ----
        // (mainloop ends with __syncthreads -> ldsB free for reuse)
        u16* tt = ldsB;                    // 64*136*2 = 17408 B <= 32768
#pragma unroll
        for (int reg = 0; reg < 4; reg++) {
            int r_loc = w * 16 + g * 4 + reg;
#pragma unroll
            for (int j = 0; j < 8; j++) {
                int col = nt * 128 + j * 16 + lm;
                tt[r_loc * 136 + j * 16 + lm] = f2bf(acc[j][reg] + bkv[col]);
            }
        }
        __syncthreads();
        int hh = nt - 8;
        int tb = m0 >> 9, tj0 = m0 & 511;
        int bh = tb * 8 + hh;
#pragma unroll
        for (int p = 0; p < 4; p++) {
            int cc = tid + 256 * p;            // 0..1023
            int dr = cc >> 3, j8 = cc & 7;
            bf16x8 o;
#pragma unroll
            for (int k = 0; k < 8; k++) o[k] = (short)tt[(j8 * 8 + k) * 136 + dr];
            *(bf16x8*)&Vtb[((size_t)bh * 128 + dr) * 512 + tj0 + j8 * 8] = o;
        }
        return;
    }

    // epilogue: D row (within frag) = g*4+reg, col = nt*128 + j*16 + lm
#pragma unroll
    for (int reg = 0; reg < 4; reg++) {
        int di = strip + g * 4 + reg;
        if (isKV || di < cnt) {
            int orow = drow[reg];
            if (!isKV && orow < 0) continue;
#pragma unroll
            for (int j = 0; j < 8; j++) {
                int col = nt * 128 + j * 16 + lm;
                float v = acc[j][reg];
                if (isKV) {
                    v += bkv[col];                     // nt<8 -> K half
                    int tb = orow >> 9, tj = orow & 511;
                    int hh = col >> 7, dd = col & 127;
                    Kb[(((size_t)(tb * 8 + hh) * 512 + tj) << 7) + dd] = f2bf(v);
                } else {
                    int pb = orow >> 10, pi = (orow >> 1) & 511, ps = orow & 1;
                    int hh = col >> 7, dd = col & 127;
                    Qb[((((size_t)(pb * 16 + ps * 8 + hh)) * 512 + pi) << 7) + dd] = f2bf(v);
                }
            }
        }
    }
}

// ---------------- W_out routed GEMM, LDS-B-staged, atomic fp32 add into Out -------------
__global__ __launch_bounds__(256) void gemm_wout(
    const u16* __restrict__ yb, const u16* __restrict__ Wout_p,
    const int* __restrict__ bucket_cnt, const int* __restrict__ buckets,
    float* __restrict__ Out)
{
    __shared__ __align__(16) u16 ldsB[2 * 8192];
    int bx = blockIdx.x;
    int tid = threadIdx.x;
    int w = tid >> 6, lane = tid & 63, lm = lane & 15, g = lane >> 4;
    int mt = bx >> 6, e = (bx & 63) >> 3, nt = bx & 7;
    int cnt = bucket_cnt[e];
    int m0 = mt * 64;
    if (m0 >= cnt) return;
    int strip = m0 + w * 16;

    int ai = strip + lm;
    int arow = buckets[e * NPAIR + (ai < cnt ? ai : cnt - 1)];
    int drow[4];
#pragma unroll
    for (int r = 0; r < 4; r++) {
        int di = strip + g * 4 + r;
        drow[r] = (di < cnt) ? buckets[e * NPAIR + di] : -1;
    }
    const u16* Aptr = yb + (size_t)arow * 1024 + g * 8;
    const u16* Bsrc = Wout_p + ((size_t)e << 20) + (((size_t)(nt * 32)) << 12);

    f32x4 acc[8];
#pragma unroll
    for (int j = 0; j < 8; j++) acc[j] = 0;

    mfma_lds_loop(Aptr, Bsrc, ldsB, tid, acc);

    // each valid pair-row appears exactly once across the grid -> exactly-once adds
#pragma unroll
    for (int reg = 0; reg < 4; reg++) {
        int orow = drow[reg];
        if (orow >= 0) {
            float* od = Out + (size_t)(orow >> 1) * 1024;
#pragma unroll
            for (int j = 0; j < 8; j++) {
                int col = nt * 128 + j * 16 + lm;
                atomic_fadd(&od[col], acc[j][reg]);
            }
        }
    }
}

// ---------------- stick-breaking flash attention, MFMA, base-2 softmax ----------------
// grid (32, 16): one i-tile per block; heavy/light pairing per CU.
// 2 barriers/iter: K/V double-buffered in LDS; T14 async-stage split; T5 setprio.
__global__ __launch_bounds__(256) void attn_kernel(
    const u16* __restrict__ Qb, const u16* __restrict__ Kb,
    const u16* __restrict__ Vtb, const float* __restrict__ gates,
    u16* __restrict__ yb)
{
    __shared__ __align__(16) u16 Qs[32 * 136];
    __shared__ __align__(16) u16 Ks[2][32 * 136];
    __shared__ __align__(16) u16 Vts[2][128 * 40];
    __shared__ __align__(16) float sw[32 * 36];
    __shared__ __align__(16) u16 wt[32 * 40];

    int combo = blockIdx.x;
    int b = combo >> 4, slot = (combo >> 3) & 1, h = combo & 7;
    int bh = b * 8 + h;
    const u16* Qbase = Qb  + ((size_t)combo << 16);
    const u16* Kbase = Kb  + ((size_t)bh << 16);
    const u16* Vbase = Vtb + ((size_t)bh << 16);

    int tid = threadIdx.x;
    int w = tid >> 6, lane = tid & 63, lm = lane & 15, g = lane >> 4;
    int mh = w >> 1, nh = w & 1, dsel = w & 1;
    int srow = tid >> 3, st = tid & 7;
    int rowlane = lane & 56;
    const float SCALE2 = 0.127517433f;   // (1/sqrt(128)) * log2(e)

    int by = blockIdx.y;
    int it = (by < 8) ? (15 - by) : (by - 8);   // heavy first; (15-y, y) pair per CU
    int i0 = it * 32;

    // K/V staging geometry (split into g2r + r2lds)
    int kr0 = tid >> 4, kc = (tid & 15) * 8;    // K: rows kr0, kr0+16
    int vr0 = tid >> 2, vc = (tid & 3) * 8;     // V: d-rows vr0, vr0+64
    bf16x8 kreg[2], vreg[2];

#define LDKV(j0_)                                                                  \
    {                                                                              \
        _Pragma("unroll")                                                          \
        for (int p = 0; p < 2; p++) {                                              \
            kreg[p] = *(const bf16x8*)&Kbase[(size_t)((j0_) + kr0 + 16 * p) * 128 + kc]; \
            vreg[p] = *(const bf16x8*)&Vbase[(size_t)(vr0 + 64 * p) * 512 + (j0_) + vc]; \
        }                                                                          \
    }
#define STKV(buf_)                                                                 \
    {                                                                              \
        _Pragma("unroll")                                                          \
        for (int p = 0; p < 2; p++) {                                              \
            *(bf16x8*)&Ks[buf_][(kr0 + 16 * p) * 136 + kc] = kreg[p];              \
            *(bf16x8*)&Vts[buf_][(vr0 + 64 * p) * 40 + vc] = vreg[p];              \
        }                                                                          \
    }

    // prologue: Q + first K/V tile into buf 0
#pragma unroll
    for (int p = 0; p < 2; p++) {
        int c = tid + 256 * p;
        int r = c >> 4, c8 = c & 15;
        *(bf16x8*)&Qs[r * 136 + c8 * 8] =
            *(const bf16x8*)&Qbase[(size_t)(i0 + r) * 128 + c8 * 8];
    }
    LDKV(i0);
    STKV(0);
    __syncthreads();

    f32x4 pacc[4];
#pragma unroll
    for (int q = 0; q < 4; q++) pacc[q] = 0;
    float running = 0.f;
    int pbuf = 0;

    for (int jt = it; jt >= 0; jt--) {
        int j0 = jt * 32;
        f32x4 sacc = 0;
        __builtin_amdgcn_s_setprio(1);
#pragma unroll
        for (int ks = 0; ks < 4; ks++) {
            bf16x8 aq = *(const bf16x8*)&Qs[(mh * 16 + lm) * 136 + ks * 32 + g * 8];
            bf16x8 bk = *(const bf16x8*)&Ks[pbuf][(nh * 16 + lm) * 136 + ks * 32 + g * 8];
            sacc = __builtin_amdgcn_mfma_f32_16x16x32_bf16(aq, bk, sacc, 0, 0, 0);
        }
        __builtin_amdgcn_s_setprio(0);
#pragma unroll
        for (int reg = 0; reg < 4; reg++)
            sw[(mh * 16 + g * 4 + reg) * 36 + nh * 16 + lm] = sacc[reg] * SCALE2;
        if (jt > 0) LDKV(j0 - 32);          // issue global loads; latency hides below
        __syncthreads();                     // sw ready
        {
            float4 sv = *(const float4*)&sw[srow * 36 + st * 4];
            float sarr[4] = {sv.x, sv.y, sv.z, sv.w};
            int ig = i0 + srow;
            float lsig[4], lb[4];
#pragma unroll
            for (int c2 = 0; c2 < 4; c2++) {
                int jg = j0 + st * 4 + c2;
                float sc = sarr[c2];                 // base-2 log space
                float a  = fabsf(sc);
                float tl = __builtin_amdgcn_logf(1.f + __builtin_amdgcn_exp2f(-a));
                lsig[c2] = (sc >= 0.f) ? -tl : sc - tl;       // log2 sigmoid
                lb[c2]   = (jg <= ig) ? -(tl + fmaxf(sc, 0.f)) : 0.f;  // log2 beta
            }
            float suf[4];
            suf[3] = 0.f;
            suf[2] = lb[3];
            suf[1] = lb[2] + lb[3];
            suf[0] = lb[1] + suf[1];
            float total = lb[0] + suf[0];
            float incl = total;
            float y1 = __shfl_down(incl, 1, 64); if (st < 7) incl += y1;
            float y2 = __shfl_down(incl, 2, 64); if (st < 6) incl += y2;
            float y4 = __shfl_down(incl, 4, 64); if (st < 4) incl += y4;
            float basev = (incl - total) + running;
            ushort4 wo;
            float wv;
            int jgc = j0 + st * 4;
            wv = (jgc + 0 <= ig) ? __builtin_amdgcn_exp2f(lsig[0] + suf[0] + basev) : 0.f; wo.x = f2bf(wv);
            wv = (jgc + 1 <= ig) ? __builtin_amdgcn_exp2f(lsig[1] + suf[1] + basev) : 0.f; wo.y = f2bf(wv);
            wv = (jgc + 2 <= ig) ? __builtin_amdgcn_exp2f(lsig[2] + suf[2] + basev) : 0.f; wo.z = f2bf(wv);
            wv = (jgc + 3 <= ig) ? __builtin_amdgcn_exp2f(lsig[3] + suf[3] + basev) : 0.f; wo.w = f2bf(wv);
            running += __shfl(incl, rowlane, 64);
            *(ushort4*)&wt[srow * 40 + st * 4] = wo;
        }
        if (jt > 0) STKV(pbuf ^ 1);          // reg->LDS into other buffer
        __syncthreads();                     // wt ready + next K/V buffer ready
        bf16x8 aw = *(const bf16x8*)&wt[(mh * 16 + lm) * 40 + g * 8];
        __builtin_amdgcn_s_setprio(1);
#pragma unroll
        for (int q = 0; q < 4; q++) {
            int dt = q * 2 + dsel;
            bf16x8 bv8 = *(const bf16x8*)&Vts[pbuf][(dt * 16 + lm) * 40 + g * 8];
            pacc[q] = __builtin_amdgcn_mfma_f32_16x16x32_bf16(aw, bv8, pacc[q], 0, 0, 0);
        }
        __builtin_amdgcn_s_setprio(0);
        pbuf ^= 1;
    }
#pragma unroll
    for (int reg = 0; reg < 4; reg++) {
        int i = i0 + mh * 16 + g * 4 + reg;
        size_t pair = ((size_t)(b * 512 + i)) * 2 + slot;
        float gt = gates[pair];
#pragma unroll
        for (int q = 0; q < 4; q++) {
            int d = (q * 2 + dsel) * 16 + lm;
            yb[pair * 1024 + h * 128 + d] = f2bf(pacc[q][reg] * gt);
        }
    }
#undef LDKV
#undef STKV
}

extern "C" void kernel_launch(void* const* d_in, const int* in_sizes, int n_in,
                              void* d_out, int out_size, void* d_ws, size_t ws_size,
                              hipStream_t stream)
{
    const float* x     = (const float*)d_in[0];
    const float* Wg    = (const float*)d_in[1];
    const float* W_in  = (const float*)d_in[2];
    const float* W_out = (const float*)d_in[3];
    const float* Wk    = (const float*)d_in[4];
    const float* bk    = (const float*)d_in[5];
    const float* Wv    = (const float*)d_in[6];
    const float* bv    = (const float*)d_in[7];

    char* ws = (char*)d_ws;
    int*   bucket_cnt = (int*)ws;
    size_t off = 256;
    float* gates = (float*)(ws + off); off += (size_t)NPAIR * 4;
    int* buckets = (int*)(ws + off);   off += (size_t)E_ * NPAIR * 4;
    float* bkv   = (float*)(ws + off); off += 2048 * 4;
    float* probs = (float*)(ws + off); off += (size_t)NTOK * E_ * 4;
    int*   eass  = (int*)(ws + off);   off += (size_t)NPAIR * 4;
    off = (off + 255) & ~(size_t)255;
    u16* xb     = (u16*)(ws + off); off += (size_t)NTOK * C_ * 2;
    u16* Wkv_p  = (u16*)(ws + off); off += (size_t)2048 * 1024 * 2;
    u16* wp     = (u16*)(ws + off); off += (size_t)E_ * 1024 * 1024 * 2;   // W_in packed
    u16* wout_p = (u16*)(ws + off); off += (size_t)E_ * 1024 * 1024 * 2;   // W_out packed
    u16* yb     = (u16*)(ws + off); off += (size_t)NPAIR * AH_ * 2;
    u16* Qbuf   = (u16*)(ws + off); off += (size_t)32 * 512 * 128 * 2;
    u16* Kbuf   = (u16*)(ws + off); off += (size_t)16 * 512 * 128 * 2;
    u16* Vtbuf  = (u16*)(ws + off); off += (size_t)16 * 128 * 512 * 2;

    pack_gate<<<2561, 256, 0, stream>>>(W_in, W_out, Wk, Wv, wp, wout_p, Wkv_p,
                                        x, Wg, xb, gates, probs, eass,
                                        (float*)d_out, bk, bv, bkv);
    route_kernel<<<1, 256, 0, stream>>>(probs, eass, bucket_cnt, buckets,
                                        (float*)d_out + (out_size - 1));

    // fused KV (256 blocks, V transposed in epilogue) + q (2048 logical blocks)
    gemm_fused<<<256 + 2048, 256, 0, stream>>>(xb, Wkv_p, bkv, wp, bucket_cnt,
                                               buckets, Kbuf, Vtbuf, Qbuf);

    attn_kernel<<<dim3(32, 16), 256, 0, stream>>>(Qbuf, Kbuf, Vtbuf, gates, yb);

    gemm_wout<<<2048, 256, 0, stream>>>(yb, wout_p, bucket_cnt, buckets,
                                        (float*)d_out);
}